// Round 1
// baseline (7124.606 us; speedup 1.0000x reference)
//
#include <hip/hip_runtime.h>
#include <hip/hip_bf16.h>

// GRU forward: B=64, T=512, I=512, U=512, out [B,T,U] fp32.
// Arch: x_all precomputed (hi/lo bf16 planes). Scan: 64 persistent WGs =
// 4 batch-groups (M=16 rows) x 16 col-WGs (32 units each). Each col-WG keeps
// its R-slice as MFMA B-fragments (hi+lo, 128 VGPRs) in registers forever.
// Per-step inter-WG h exchange via global hi/lo h fragments + per-(group,step)
// arrival counters (device-scope atomics). All 64 WGs co-resident (512 waves).

typedef float f32x4 __attribute__((ext_vector_type(4)));
typedef short bf16x8 __attribute__((ext_vector_type(8)));

#define MFMA16(a, b, c) __builtin_amdgcn_mfma_f32_16x16x32_bf16((a), (b), (c), 0, 0, 0)

__device__ __forceinline__ float bf2f(__hip_bfloat16 v) { return __bfloat162float(v); }

__device__ __forceinline__ void split_bf(float v, short& hi, short& lo) {
    __hip_bfloat16 h = __float2bfloat16(v);
    float rem = v - __bfloat162float(h);
    __hip_bfloat16 l = __float2bfloat16(rem);
    hi = __builtin_bit_cast(short, h);
    lo = __builtin_bit_cast(short, l);
}

// ---------------------------------------------------------------- zero scratch
__global__ void zero_kernel(float* p, int n) {
    int i = blockIdx.x * blockDim.x + threadIdx.x;
    int stride = gridDim.x * blockDim.x;
    for (; i < n; i += stride) p[i] = 0.f;
}

// ------------------------------------------------- pack weights into B-frags
// Source W [512 x 1536] fp32. Frag (tile,kk): lane l element e =
// W[kk*32 + 8*(l>>4) + e][tile*16 + (l&15)], stored hi/lo bf16 planes.
__global__ __launch_bounds__(64, 1) void pack_w_kernel(const float* __restrict__ W,
                                                       short* __restrict__ dhi,
                                                       short* __restrict__ dlo) {
    int bid = blockIdx.x;   // tile*16 + kk, 0..1535
    int lane = threadIdx.x; // 0..63
    int col = (bid >> 4) * 16 + (lane & 15);
    int kbase = (bid & 15) * 32 + (lane >> 4) * 8;
    bf16x8 vh, vl;
#pragma unroll
    for (int e = 0; e < 8; e++) {
        float v = W[(kbase + e) * 1536 + col];
        short h, l;
        split_bf(v, h, l);
        vh[e] = h;
        vl[e] = l;
    }
    *(bf16x8*)(dhi + bid * 512 + lane * 8) = vh;
    *(bf16x8*)(dlo + bid * 512 + lane * 8) = vl;
}

// ------------------------------------------------------------- x_all GEMM
// x_all[r=b*512+t][1536] = inputs[r][:512] @ kernel + bias[0], hi/lo bf16.
// Block = 4 waves, one 16-row tile; wave w handles col-tiles [24w, 24w+24).
__global__ __launch_bounds__(256, 2) void xgemm_kernel(
    const float* __restrict__ A, const short* __restrict__ wkh,
    const short* __restrict__ wkl, const float* __restrict__ bias,
    __hip_bfloat16* __restrict__ xhi, __hip_bfloat16* __restrict__ xlo, int xlo_en) {
    int rt = blockIdx.x; // 0..2047
    int wave = threadIdx.x >> 6, lane = threadIdx.x & 63;
    int arow = rt * 16 + (lane & 15);
    const float* abase = A + arow * 512 + (lane >> 4) * 8;

    f32x4 acc[24];
#pragma unroll
    for (int j = 0; j < 24; j++) acc[j] = (f32x4){0.f, 0.f, 0.f, 0.f};

#pragma unroll 1
    for (int kk = 0; kk < 16; kk++) {
        f32x4 a0 = *(const f32x4*)(abase + kk * 32);
        f32x4 a1 = *(const f32x4*)(abase + kk * 32 + 4);
        bf16x8 ah, al;
#pragma unroll
        for (int e = 0; e < 8; e++) {
            float v = (e < 4) ? a0[e] : a1[e - 4];
            short h, l;
            split_bf(v, h, l);
            ah[e] = h;
            al[e] = l;
        }
#pragma unroll
        for (int j = 0; j < 24; j++) {
            int frag = (wave * 24 + j) * 16 + kk;
            bf16x8 bh = *(const bf16x8*)(wkh + frag * 512 + lane * 8);
            bf16x8 bl = *(const bf16x8*)(wkl + frag * 512 + lane * 8);
            acc[j] = MFMA16(ah, bh, acc[j]);
            acc[j] = MFMA16(al, bh, acc[j]);
            acc[j] = MFMA16(ah, bl, acc[j]);
        }
    }
    int colin = lane & 15, r4 = (lane >> 4) * 4;
#pragma unroll
    for (int j = 0; j < 24; j++) {
        int colg = (wave * 24 + j) * 16 + colin;
        float bv = bias[colg];
#pragma unroll
        for (int r = 0; r < 4; r++) {
            float v = acc[j][r] + bv;
            int rowg = rt * 16 + r4 + r;
            short h, l;
            split_bf(v, h, l);
            xhi[rowg * 1536 + colg] = __builtin_bit_cast(__hip_bfloat16, h);
            if (xlo_en) xlo[rowg * 1536 + colg] = __builtin_bit_cast(__hip_bfloat16, l);
        }
    }
}

// ------------------------------------------------------------------ scan
// 64 blocks x 512 threads. block: g = bid&3 (batch group, rows 16g..16g+15),
// w = bid>>2 (units 32w..32w+31; col-tiles z:{2w,2w+1} r:{32+..} h:{64+..}).
// Waves 0-5: MFMA (one tile each, R-slice in regs). Waves 6-7: x prefetch.
// Threads 0-255: gates, 2 units each; persistent fp32 h in regs.
__global__ __launch_bounds__(512, 2) void scan_kernel(
    const __hip_bfloat16* __restrict__ xhi, const __hip_bfloat16* __restrict__ xlo,
    const short* __restrict__ wrh, const short* __restrict__ wrl,
    const float* __restrict__ bias, float* __restrict__ out,
    __hip_bfloat16* hbuf, int* cnt, int xlo_en) {
    const int bid = blockIdx.x;
    const int g = bid & 3;
    const int w = bid >> 2;
    const int tid = threadIdx.x;
    const int wave = tid >> 6;
    const int lane = tid & 63;

    __shared__ __align__(16) float pre[6][16][16];
    __shared__ __align__(16) __hip_bfloat16 xsh[2][16][104]; // padded stride
    __shared__ float rb[96];

    if (tid < 96) {
        int seg = tid >> 5, u = tid & 31;
        rb[tid] = bias[1536 + seg * 512 + w * 32 + u];
    }

    // persistent B fragments (hi+lo) for waves 0-5
    bf16x8 bh[16], bl[16];
    if (wave < 6) {
        int tile = (wave >> 1) * 32 + 2 * w + (wave & 1);
#pragma unroll
        for (int kk = 0; kk < 16; kk++) {
            bh[kk] = *(const bf16x8*)(wrh + (tile * 16 + kk) * 512 + lane * 8);
            bl[kk] = *(const bf16x8*)(wrl + (tile * 16 + kk) * 512 + lane * 8);
        }
    }

    const int grow = tid & 15; // gate thread: batch row
    const int q = tid >> 4;    // gate thread: unit pair 0..15 (tid<256)
    float h0 = 0.f, h1 = 0.f;
    const int wlane = grow + 16 * (q >> 2); // frag lane for h writes
    const int woff = (2 * q) & 7;           // element offset in frag lane

    __syncthreads();

    const int HB = 8192; // plane stride (elems): 16 kk * 64 lanes * 8
    for (int t = 0; t < 512; t++) {
        const int rpar = t & 1;
        // ---------------- phase A: MFMA + x prefetch ----------------
        if (wave < 6) {
            const __hip_bfloat16* hH = hbuf + (rpar * 4 + g) * 2 * HB;
            const __hip_bfloat16* hL = hH + HB;
            f32x4 aa = (f32x4){0.f, 0.f, 0.f, 0.f};
            f32x4 ab = (f32x4){0.f, 0.f, 0.f, 0.f};
            f32x4 ac = (f32x4){0.f, 0.f, 0.f, 0.f};
#pragma unroll
            for (int kk = 0; kk < 16; kk++) {
                bf16x8 ah = *(const bf16x8*)(hH + kk * 512 + lane * 8);
                bf16x8 al = *(const bf16x8*)(hL + kk * 512 + lane * 8);
                aa = MFMA16(ah, bh[kk], aa);
                ab = MFMA16(al, bh[kk], ab);
                ac = MFMA16(ah, bl[kk], ac);
            }
            f32x4 acc = aa + ab;
            acc = acc + ac;
            int col = lane & 15, r4 = (lane >> 4) * 4;
            *(f32x4*)&pre[wave][col][r4] = acc;
        } else {
            int it = tid - 384; // 0..127
            int nch = xlo_en ? 384 : 192;
            for (int c = it; c < nch; c += 128) {
                int plane = c / 192;
                int rem = c % 192;
                int row_ = rem / 12;
                int cw = rem % 12;
                int seg = cw >> 2, off = cw & 3;
                int rglob = (g * 16 + row_) * 512 + t;
                const __hip_bfloat16* src =
                    (plane ? xlo : xhi) + rglob * 1536 + seg * 512 + w * 32 + off * 8;
                *(bf16x8*)&xsh[plane][row_][seg * 32 + off * 8] = *(const bf16x8*)src;
            }
        }
        __syncthreads();
        // ---------------- phase B: gates ----------------
        if (tid < 256) {
            const int wpar = 1 - rpar;
            __hip_bfloat16* hw =
                hbuf + ((wpar * 4 + g) * 2 + 0) * HB + w * 512 + wlane * 8 + woff;
            __hip_bfloat16* hwl = hw + HB;
            float hold[2] = {h0, h1};
            float hn[2];
#pragma unroll
            for (int j = 0; j < 2; j++) {
                int uu = 2 * q + j;
                int slot = uu >> 4, c16 = uu & 15;
                float xz = bf2f(xsh[0][grow][uu]);
                float xr = bf2f(xsh[0][grow][32 + uu]);
                float xh = bf2f(xsh[0][grow][64 + uu]);
                if (xlo_en) {
                    xz += bf2f(xsh[1][grow][uu]);
                    xr += bf2f(xsh[1][grow][32 + uu]);
                    xh += bf2f(xsh[1][grow][64 + uu]);
                }
                float rz = pre[slot][c16][grow] + rb[uu];
                float rr = pre[2 + slot][c16][grow] + rb[32 + uu];
                float rh = pre[4 + slot][c16][grow] + rb[64 + uu];
                float z = 1.f / (1.f + expf(-(xz + rz)));
                float r = 1.f / (1.f + expf(-(xr + rr)));
                float hh = tanhf(xh + r * rh);
                hn[j] = z * hold[j] + (1.f - z) * hh;
            }
            h0 = hn[0];
            h1 = hn[1];
            int obase = ((g * 16 + grow) * 512 + t) * 512 + w * 32 + 2 * q;
            out[obase] = hn[0];
            out[obase + 1] = hn[1];
            short hi0, lo0, hi1, lo1;
            split_bf(hn[0], hi0, lo0);
            split_bf(hn[1], hi1, lo1);
            hw[0] = __builtin_bit_cast(__hip_bfloat16, hi0);
            hw[1] = __builtin_bit_cast(__hip_bfloat16, hi1);
            hwl[0] = __builtin_bit_cast(__hip_bfloat16, lo0);
            hwl[1] = __builtin_bit_cast(__hip_bfloat16, lo1);
        }
        if (t == 511) break;
        __threadfence(); // make h stores agent-visible
        __syncthreads();
        if (tid == 0) {
            int idx = g * 512 + t;
            __hip_atomic_fetch_add(&cnt[idx], 1, __ATOMIC_ACQ_REL, __HIP_MEMORY_SCOPE_AGENT);
            long spins = 0;
            while (__hip_atomic_load(&cnt[idx], __ATOMIC_ACQUIRE, __HIP_MEMORY_SCOPE_AGENT) <
                   16) {
                if (++spins > (1L << 24)) break; // bailout (never hit if correct)
                __builtin_amdgcn_s_sleep(1);
            }
        }
        __syncthreads();
    }
}

extern "C" void kernel_launch(void* const* d_in, const int* in_sizes, int n_in,
                              void* d_out, int out_size, void* d_ws, size_t ws_size,
                              hipStream_t stream) {
    const float* inputs = (const float*)d_in[0]; // [64,512,512]
    const float* wk = (const float*)d_in[1];     // [512,1536]
    const float* wr = (const float*)d_in[2];     // [512,1536]
    const float* bias = (const float*)d_in[3];   // [2,1536]
    float* out = (float*)d_out;
    char* ws = (char*)d_ws;

    const size_t SZ_W = 512UL * 1536 * 2; // 1.5 MiB per plane
    short* wk_hi = (short*)(ws);
    short* wk_lo = (short*)(ws + SZ_W);
    short* wr_hi = (short*)(ws + 2 * SZ_W);
    short* wr_lo = (short*)(ws + 3 * SZ_W);
    __hip_bfloat16* hbuf = (__hip_bfloat16*)(ws + 4 * SZ_W); // 256 KiB
    int* cnt = (int*)(ws + 4 * SZ_W + 262144);               // 8 KiB
    char* xbase = ws + 4 * SZ_W + 262144 + 8192;
    const size_t SZ_X = 32768UL * 1536 * 2; // 96 MiB per plane
    __hip_bfloat16* xhi = (__hip_bfloat16*)xbase;
    __hip_bfloat16* xlo = (__hip_bfloat16*)(xbase + SZ_X);

    size_t need_min = (size_t)(xbase - ws) + SZ_X;
    size_t need_full = need_min + SZ_X;
    if (ws_size < need_min) return; // cannot run without scratch; fail visibly
    int xlo_en = (ws_size >= need_full) ? 1 : 0;

    zero_kernel<<<256, 256, 0, stream>>>((float*)hbuf, (262144 + 8192) / 4);
    pack_w_kernel<<<1536, 64, 0, stream>>>(wk, wk_hi, wk_lo);
    pack_w_kernel<<<1536, 64, 0, stream>>>(wr, wr_hi, wr_lo);
    xgemm_kernel<<<2048, 256, 0, stream>>>(inputs, wk_hi, wk_lo, bias, xhi, xlo, xlo_en);
    scan_kernel<<<64, 512, 0, stream>>>(xhi, xlo, wr_hi, wr_lo, bias, out, hbuf, cnt,
                                        xlo_en);
}

// Round 2
// 3701.936 us; speedup vs baseline: 1.9246x; 1.9246x over previous
//
#include <hip/hip_runtime.h>
#include <hip/hip_bf16.h>

// GRU forward: B=64, T=512, I=512, U=512, out [B,T,U] fp32.
// Arch: x_all precomputed (hi/lo bf16 planes). Scan: 64 persistent WGs =
// 4 batch-groups (M=16 rows) x 16 col-WGs (32 units each). Each col-WG keeps
// its R-slice as MFMA B-fragments (hi+lo, 128 VGPRs) in registers forever.
// Per-step inter-WG h exchange via DEVICE-COHERENT (sc1) per-access loads and
// stores of global hi/lo h fragments + per-(group,step) arrival counters with
// RELAXED agent atomics. No threadfence: __syncthreads drains vmcnt before the
// counter increment, and sc1 accesses hit the device coherence point directly,
// avoiding the per-step buffer_wbl2/buffer_inv L2 maintenance that made round-1
// run at 13 us/step with all pipes <1.3% busy.

typedef float f32x4 __attribute__((ext_vector_type(4)));
typedef short bf16x8 __attribute__((ext_vector_type(8)));
typedef unsigned long long u64;
typedef unsigned int u32;

#define MFMA16(a, b, c) __builtin_amdgcn_mfma_f32_16x16x32_bf16((a), (b), (c), 0, 0, 0)

__device__ __forceinline__ float bf2f(__hip_bfloat16 v) { return __bfloat162float(v); }

__device__ __forceinline__ void split_bf(float v, short& hi, short& lo) {
    __hip_bfloat16 h = __float2bfloat16(v);
    float rem = v - __bfloat162float(h);
    __hip_bfloat16 l = __float2bfloat16(rem);
    hi = __builtin_bit_cast(short, h);
    lo = __builtin_bit_cast(short, l);
}

struct U64x2 {
    u64 a, b;
};

// Device-coherent 16B load as two sc1 dwordx2 loads (agent scope, relaxed).
__device__ __forceinline__ bf16x8 load_frag_sc1(const __hip_bfloat16* p) {
    const u64* q = (const u64*)p;
    U64x2 t;
    t.a = __hip_atomic_load(q, __ATOMIC_RELAXED, __HIP_MEMORY_SCOPE_AGENT);
    t.b = __hip_atomic_load(q + 1, __ATOMIC_RELAXED, __HIP_MEMORY_SCOPE_AGENT);
    return __builtin_bit_cast(bf16x8, t);
}

__device__ __forceinline__ void store_pair_sc1(__hip_bfloat16* p, short e0, short e1) {
    u32 v = (u32)(unsigned short)e0 | ((u32)(unsigned short)e1 << 16);
    __hip_atomic_store((u32*)p, v, __ATOMIC_RELAXED, __HIP_MEMORY_SCOPE_AGENT);
}

// ---------------------------------------------------------------- zero scratch
__global__ void zero_kernel(float* p, int n) {
    int i = blockIdx.x * blockDim.x + threadIdx.x;
    int stride = gridDim.x * blockDim.x;
    for (; i < n; i += stride) p[i] = 0.f;
}

// ------------------------------------------------- pack weights into B-frags
// Source W [512 x 1536] fp32. Frag (tile,kk): lane l element e =
// W[kk*32 + 8*(l>>4) + e][tile*16 + (l&15)], stored hi/lo bf16 planes.
__global__ __launch_bounds__(64, 1) void pack_w_kernel(const float* __restrict__ W,
                                                       short* __restrict__ dhi,
                                                       short* __restrict__ dlo) {
    int bid = blockIdx.x;   // tile*16 + kk, 0..1535
    int lane = threadIdx.x; // 0..63
    int col = (bid >> 4) * 16 + (lane & 15);
    int kbase = (bid & 15) * 32 + (lane >> 4) * 8;
    bf16x8 vh, vl;
#pragma unroll
    for (int e = 0; e < 8; e++) {
        float v = W[(kbase + e) * 1536 + col];
        short h, l;
        split_bf(v, h, l);
        vh[e] = h;
        vl[e] = l;
    }
    *(bf16x8*)(dhi + bid * 512 + lane * 8) = vh;
    *(bf16x8*)(dlo + bid * 512 + lane * 8) = vl;
}

// ------------------------------------------------------------- x_all GEMM
// x_all[r=b*512+t][1536] = inputs[r][:512] @ kernel + bias[0], hi/lo bf16.
// Block = 4 waves, one 16-row tile; wave w handles col-tiles [24w, 24w+24).
__global__ __launch_bounds__(256, 2) void xgemm_kernel(
    const float* __restrict__ A, const short* __restrict__ wkh,
    const short* __restrict__ wkl, const float* __restrict__ bias,
    __hip_bfloat16* __restrict__ xhi, __hip_bfloat16* __restrict__ xlo, int xlo_en) {
    int rt = blockIdx.x; // 0..2047
    int wave = threadIdx.x >> 6, lane = threadIdx.x & 63;
    int arow = rt * 16 + (lane & 15);
    const float* abase = A + arow * 512 + (lane >> 4) * 8;

    f32x4 acc[24];
#pragma unroll
    for (int j = 0; j < 24; j++) acc[j] = (f32x4){0.f, 0.f, 0.f, 0.f};

#pragma unroll 1
    for (int kk = 0; kk < 16; kk++) {
        f32x4 a0 = *(const f32x4*)(abase + kk * 32);
        f32x4 a1 = *(const f32x4*)(abase + kk * 32 + 4);
        bf16x8 ah, al;
#pragma unroll
        for (int e = 0; e < 8; e++) {
            float v = (e < 4) ? a0[e] : a1[e - 4];
            short h, l;
            split_bf(v, h, l);
            ah[e] = h;
            al[e] = l;
        }
#pragma unroll
        for (int j = 0; j < 24; j++) {
            int frag = (wave * 24 + j) * 16 + kk;
            bf16x8 bh = *(const bf16x8*)(wkh + frag * 512 + lane * 8);
            bf16x8 bl = *(const bf16x8*)(wkl + frag * 512 + lane * 8);
            acc[j] = MFMA16(ah, bh, acc[j]);
            acc[j] = MFMA16(al, bh, acc[j]);
            acc[j] = MFMA16(ah, bl, acc[j]);
        }
    }
    int colin = lane & 15, r4 = (lane >> 4) * 4;
#pragma unroll
    for (int j = 0; j < 24; j++) {
        int colg = (wave * 24 + j) * 16 + colin;
        float bv = bias[colg];
#pragma unroll
        for (int r = 0; r < 4; r++) {
            float v = acc[j][r] + bv;
            int rowg = rt * 16 + r4 + r;
            short h, l;
            split_bf(v, h, l);
            xhi[rowg * 1536 + colg] = __builtin_bit_cast(__hip_bfloat16, h);
            if (xlo_en) xlo[rowg * 1536 + colg] = __builtin_bit_cast(__hip_bfloat16, l);
        }
    }
}

// ------------------------------------------------------------------ scan
// 64 blocks x 512 threads. block: g = bid&3 (batch group, rows 16g..16g+15),
// w = bid>>2 (units 32w..32w+31; col-tiles z:{2w,2w+1} r:{32+..} h:{64+..}).
// Waves 0-5: MFMA (one tile each, R-slice in regs). Waves 6-7: x prefetch.
// Threads 0-255: gates, 2 units each; persistent fp32 h in regs.
__global__ __launch_bounds__(512, 2) void scan_kernel(
    const __hip_bfloat16* __restrict__ xhi, const __hip_bfloat16* __restrict__ xlo,
    const short* __restrict__ wrh, const short* __restrict__ wrl,
    const float* __restrict__ bias, float* __restrict__ out,
    __hip_bfloat16* hbuf, int* cnt, int xlo_en) {
    const int bid = blockIdx.x;
    const int g = bid & 3;
    const int w = bid >> 2;
    const int tid = threadIdx.x;
    const int wave = tid >> 6;
    const int lane = tid & 63;

    __shared__ __align__(16) float pre[6][16][16];
    __shared__ __align__(16) __hip_bfloat16 xsh[2][16][104]; // padded stride
    __shared__ float rb[96];

    if (tid < 96) {
        int seg = tid >> 5, u = tid & 31;
        rb[tid] = bias[1536 + seg * 512 + w * 32 + u];
    }

    // persistent B fragments (hi+lo) for waves 0-5
    bf16x8 bh[16], bl[16];
    if (wave < 6) {
        int tile = (wave >> 1) * 32 + 2 * w + (wave & 1);
#pragma unroll
        for (int kk = 0; kk < 16; kk++) {
            bh[kk] = *(const bf16x8*)(wrh + (tile * 16 + kk) * 512 + lane * 8);
            bl[kk] = *(const bf16x8*)(wrl + (tile * 16 + kk) * 512 + lane * 8);
        }
    }

    const int grow = tid & 15; // gate thread: batch row
    const int q = tid >> 4;    // gate thread: unit pair 0..15 (tid<256)
    float h0 = 0.f, h1 = 0.f;
    const int wlane = grow + 16 * (q >> 2); // frag lane for h writes
    const int woff = (2 * q) & 7;           // element offset in frag lane

    __syncthreads();

    const int HB = 8192; // plane stride (elems): 16 kk * 64 lanes * 8
    for (int t = 0; t < 512; t++) {
        const int rpar = t & 1;
        // ---------------- phase A: MFMA + x prefetch ----------------
        if (wave < 6) {
            const __hip_bfloat16* hH = hbuf + (rpar * 4 + g) * 2 * HB;
            const __hip_bfloat16* hL = hH + HB;
            f32x4 aa = (f32x4){0.f, 0.f, 0.f, 0.f};
            f32x4 ab = (f32x4){0.f, 0.f, 0.f, 0.f};
            f32x4 ac = (f32x4){0.f, 0.f, 0.f, 0.f};
#pragma unroll
            for (int kk = 0; kk < 16; kk++) {
                bf16x8 ah = load_frag_sc1(hH + kk * 512 + lane * 8);
                bf16x8 al = load_frag_sc1(hL + kk * 512 + lane * 8);
                aa = MFMA16(ah, bh[kk], aa);
                ab = MFMA16(al, bh[kk], ab);
                ac = MFMA16(ah, bl[kk], ac);
            }
            f32x4 acc = aa + ab;
            acc = acc + ac;
            int col = lane & 15, r4 = (lane >> 4) * 4;
            *(f32x4*)&pre[wave][col][r4] = acc;
        } else {
            int it = tid - 384; // 0..127
            int nch = xlo_en ? 384 : 192;
            for (int c = it; c < nch; c += 128) {
                int plane = c / 192;
                int rem = c % 192;
                int row_ = rem / 12;
                int cw = rem % 12;
                int seg = cw >> 2, off = cw & 3;
                int rglob = (g * 16 + row_) * 512 + t;
                const __hip_bfloat16* src =
                    (plane ? xlo : xhi) + rglob * 1536 + seg * 512 + w * 32 + off * 8;
                *(bf16x8*)&xsh[plane][row_][seg * 32 + off * 8] = *(const bf16x8*)src;
            }
        }
        __syncthreads();
        // ---------------- phase B: gates ----------------
        if (tid < 256) {
            const int wpar = 1 - rpar;
            __hip_bfloat16* hw =
                hbuf + ((wpar * 4 + g) * 2 + 0) * HB + w * 512 + wlane * 8 + woff;
            __hip_bfloat16* hwl = hw + HB;
            float hold[2] = {h0, h1};
            float hn[2];
#pragma unroll
            for (int j = 0; j < 2; j++) {
                int uu = 2 * q + j;
                int slot = uu >> 4, c16 = uu & 15;
                float xz = bf2f(xsh[0][grow][uu]);
                float xr = bf2f(xsh[0][grow][32 + uu]);
                float xh = bf2f(xsh[0][grow][64 + uu]);
                if (xlo_en) {
                    xz += bf2f(xsh[1][grow][uu]);
                    xr += bf2f(xsh[1][grow][32 + uu]);
                    xh += bf2f(xsh[1][grow][64 + uu]);
                }
                float rz = pre[slot][c16][grow] + rb[uu];
                float rr = pre[2 + slot][c16][grow] + rb[32 + uu];
                float rh = pre[4 + slot][c16][grow] + rb[64 + uu];
                float z = 1.f / (1.f + expf(-(xz + rz)));
                float r = 1.f / (1.f + expf(-(xr + rr)));
                float hh = tanhf(xh + r * rh);
                hn[j] = z * hold[j] + (1.f - z) * hh;
            }
            h0 = hn[0];
            h1 = hn[1];
            int obase = ((g * 16 + grow) * 512 + t) * 512 + w * 32 + 2 * q;
            out[obase] = hn[0];
            out[obase + 1] = hn[1];
            short hi0, lo0, hi1, lo1;
            split_bf(hn[0], hi0, lo0);
            split_bf(hn[1], hi1, lo1);
            store_pair_sc1(hw, hi0, hi1);
            store_pair_sc1(hwl, lo0, lo1);
        }
        if (t == 511) break;
        // __syncthreads drains vmcnt(0) for ALL threads' sc1 h-stores (device
        // visible on completion), so tid 0's relaxed increment is a release in
        // effect without any L2 writeback.
        __syncthreads();
        if (tid == 0) {
            int idx = g * 512 + t;
            __hip_atomic_fetch_add(&cnt[idx], 1, __ATOMIC_RELAXED, __HIP_MEMORY_SCOPE_AGENT);
            long spins = 0;
            while (__hip_atomic_load(&cnt[idx], __ATOMIC_RELAXED, __HIP_MEMORY_SCOPE_AGENT) <
                   16) {
                if (++spins > (1L << 24)) break; // bailout (never hit if correct)
                __builtin_amdgcn_s_sleep(1);
            }
        }
        __syncthreads();
    }
}

extern "C" void kernel_launch(void* const* d_in, const int* in_sizes, int n_in,
                              void* d_out, int out_size, void* d_ws, size_t ws_size,
                              hipStream_t stream) {
    const float* inputs = (const float*)d_in[0]; // [64,512,512]
    const float* wk = (const float*)d_in[1];     // [512,1536]
    const float* wr = (const float*)d_in[2];     // [512,1536]
    const float* bias = (const float*)d_in[3];   // [2,1536]
    float* out = (float*)d_out;
    char* ws = (char*)d_ws;

    const size_t SZ_W = 512UL * 1536 * 2; // 1.5 MiB per plane
    short* wk_hi = (short*)(ws);
    short* wk_lo = (short*)(ws + SZ_W);
    short* wr_hi = (short*)(ws + 2 * SZ_W);
    short* wr_lo = (short*)(ws + 3 * SZ_W);
    __hip_bfloat16* hbuf = (__hip_bfloat16*)(ws + 4 * SZ_W); // 256 KiB
    int* cnt = (int*)(ws + 4 * SZ_W + 262144);               // 8 KiB
    char* xbase = ws + 4 * SZ_W + 262144 + 8192;
    const size_t SZ_X = 32768UL * 1536 * 2; // 96 MiB per plane
    __hip_bfloat16* xhi = (__hip_bfloat16*)xbase;
    __hip_bfloat16* xlo = (__hip_bfloat16*)(xbase + SZ_X);

    size_t need_min = (size_t)(xbase - ws) + SZ_X;
    size_t need_full = need_min + SZ_X;
    if (ws_size < need_min) return; // cannot run without scratch; fail visibly
    int xlo_en = (ws_size >= need_full) ? 1 : 0;

    zero_kernel<<<256, 256, 0, stream>>>((float*)hbuf, (262144 + 8192) / 4);
    pack_w_kernel<<<1536, 64, 0, stream>>>(wk, wk_hi, wk_lo);
    pack_w_kernel<<<1536, 64, 0, stream>>>(wr, wr_hi, wr_lo);
    xgemm_kernel<<<2048, 256, 0, stream>>>(inputs, wk_hi, wk_lo, bias, xhi, xlo, xlo_en);
    scan_kernel<<<64, 512, 0, stream>>>(xhi, xlo, wr_hi, wr_lo, bias, out, hbuf, cnt,
                                        xlo_en);
}